// Round 1
// 2186.039 us; speedup vs baseline: 1.0546x; 1.0546x over previous
//
#include <hip/hip_runtime.h>
#include <math.h>

// Problem constants
#define Bn  4
#define Sn  2048
#define Hn  768
#define NHn 12
#define DHn 64
#define WHn 128
#define MR  (Bn * Sn)      // 8192 rows
#define EPSf 1e-12f

// ---------------------------------------------------------------------------
// Generic tiled fp32 GEMM: C[M,N] = A[M,K] @ W[K,N] + bias[N]
// 64x64 tile, 256 threads, 4x4 micro-tile per thread, K-step 16.
// ---------------------------------------------------------------------------
__global__ __launch_bounds__(256) void proj_gemm(const float* __restrict__ A,
                                                 const float* __restrict__ W,
                                                 const float* __restrict__ bias,
                                                 float* __restrict__ C,
                                                 int M, int N, int K) {
    __shared__ float At[16][68];   // [k][row]
    __shared__ float Bs[16][68];   // [k][col]
    const int tid = threadIdx.x;
    const int tx = tid & 15, ty = tid >> 4;
    const int row0 = blockIdx.y << 6, col0 = blockIdx.x << 6;
    float acc[4][4] = {};

    for (int k0 = 0; k0 < K; k0 += 16) {
        {
            const int r = tid >> 2;            // 0..63
            const int c = (tid & 3) << 2;      // 0,4,8,12
            float4 av = *(const float4*)(A + (size_t)(row0 + r) * K + (k0 + c));
            At[c + 0][r] = av.x; At[c + 1][r] = av.y;
            At[c + 2][r] = av.z; At[c + 3][r] = av.w;
            const int wr = tid >> 4;           // 0..15
            const int wc = (tid & 15) << 2;    // 0..60
            *(float4*)&Bs[wr][wc] =
                *(const float4*)(W + (size_t)(k0 + wr) * N + (col0 + wc));
        }
        __syncthreads();
#pragma unroll
        for (int kk = 0; kk < 16; ++kk) {
            float4 a4 = *(const float4*)&At[kk][ty << 2];
            float4 b4 = *(const float4*)&Bs[kk][tx << 2];
            const float a[4] = {a4.x, a4.y, a4.z, a4.w};
            const float b[4] = {b4.x, b4.y, b4.z, b4.w};
#pragma unroll
            for (int i = 0; i < 4; ++i)
#pragma unroll
                for (int j = 0; j < 4; ++j) acc[i][j] += a[i] * b[j];
        }
        __syncthreads();
    }
#pragma unroll
    for (int i = 0; i < 4; ++i) {
        const int r = row0 + (ty << 2) + i;
        const int c = col0 + (tx << 2);
        float4 o;
        o.x = acc[i][0] + bias[c + 0];
        o.y = acc[i][1] + bias[c + 1];
        o.z = acc[i][2] + bias[c + 2];
        o.w = acc[i][3] + bias[c + 3];
        *(float4*)(C + (size_t)r * N + c) = o;
    }
}

// ---------------------------------------------------------------------------
// Gate head: per row of g[8192,128]: LayerNorm -> relu -> @Wg2[128,12]+bg2
// -> sigmoid -> gates[8192,12]
// ---------------------------------------------------------------------------
__global__ __launch_bounds__(128) void gate_kernel(const float* __restrict__ g,
                                                   const float* __restrict__ lw,
                                                   const float* __restrict__ lb,
                                                   const float* __restrict__ Wg2,
                                                   const float* __restrict__ bg2,
                                                   float* __restrict__ gates) {
    const int row = blockIdx.x;    // 0..8191
    const int t = threadIdx.x;     // 0..127
    __shared__ float red[128];
    __shared__ float ys[128];
    const float x = g[(size_t)row * WHn + t];
    red[t] = x; __syncthreads();
    for (int s2 = 64; s2 > 0; s2 >>= 1) {
        if (t < s2) red[t] += red[t + s2];
        __syncthreads();
    }
    const float mu = red[0] * (1.0f / WHn);
    __syncthreads();
    const float d = x - mu;
    red[t] = d * d; __syncthreads();
    for (int s2 = 64; s2 > 0; s2 >>= 1) {
        if (t < s2) red[t] += red[t + s2];
        __syncthreads();
    }
    const float var = red[0] * (1.0f / WHn);
    float y = d * rsqrtf(var + EPSf) * lw[t] + lb[t];
    y = fmaxf(y, 0.0f);
    ys[t] = y; __syncthreads();
    if (t < NHn) {
        float acc = bg2[t];
        for (int w = 0; w < WHn; ++w) acc += ys[w] * Wg2[w * NHn + t];
        gates[(size_t)row * NHn + t] = 1.0f / (1.0f + __expf(-acc));
    }
}

// ---------------------------------------------------------------------------
// Fused attention: per (bh, 64-row q-strip):
//   Pass 1: QK^T tiles -> gate*0.125 + mask -> write RAW scores to probs,
//           maintain per-row online (max, sum-exp) in registers.
//   Pass 2: read raw tiles back (L2), normalize -> final probs write,
//           and accumulate PV through LDS into ctx.
// probs traffic: 3 x 805MB (vs 4 x with separate softmax+pv kernels).
// ---------------------------------------------------------------------------
__global__ __launch_bounds__(256) void attn_fused(const float* __restrict__ qb,
                                                  const float* __restrict__ kb,
                                                  const float* __restrict__ vb,
                                                  const float* __restrict__ gates,
                                                  const float* __restrict__ amask,
                                                  float* __restrict__ probs,
                                                  float* __restrict__ ctx) {
    __shared__ float SA[64][68];   // pass1: Qt [d][q]   pass2: Ps [q][k]
    __shared__ float SB[64][68];   // pass1: Kt [d][k]   pass2: Vs [k][d]
    const int tid = threadIdx.x;
    const int tx = tid & 15, ty = tid >> 4;
    const int bh = blockIdx.y;
    const int b = bh / NHn, h = bh - b * NHn;
    const int q0 = blockIdx.x << 6;
    const float* Q = qb + (size_t)b * Sn * Hn + (size_t)h * DHn;
    const float* K = kb + (size_t)b * Sn * Hn + (size_t)h * DHn;
    const float* V = vb + (size_t)b * Sn * Hn + (size_t)h * DHn;
    float* P = probs + (size_t)bh * Sn * Sn;

    // stage Q strip once: Qt[d][q]
#pragma unroll
    for (int t2 = 0; t2 < 4; ++t2) {
        const int f = tid + (t2 << 8);
        const int r = f >> 4;            // 0..63
        const int c = (f & 15) << 2;     // 0..60
        float4 qv = *(const float4*)(Q + (size_t)(q0 + r) * Hn + c);
        SA[c + 0][r] = qv.x; SA[c + 1][r] = qv.y;
        SA[c + 2][r] = qv.z; SA[c + 3][r] = qv.w;
    }

    float gt[4];
#pragma unroll
    for (int i = 0; i < 4; ++i)
        gt[i] = gates[((size_t)b * Sn + q0 + (ty << 2) + i) * NHn + h] * 0.125f;

    float mrow[4] = {-INFINITY, -INFINITY, -INFINITY, -INFINITY};
    float lrow[4] = {0.f, 0.f, 0.f, 0.f};

    // ---- Pass 1: raw scores + online (m,l) ----
    for (int kt = 0; kt < 32; ++kt) {
        const int c0 = kt << 6;
        __syncthreads();               // protect SB vs previous iter readers
#pragma unroll
        for (int t2 = 0; t2 < 4; ++t2) {
            const int f = tid + (t2 << 8);
            const int r = f >> 4;
            const int c = (f & 15) << 2;
            float4 kv = *(const float4*)(K + (size_t)(c0 + r) * Hn + c);
            SB[c + 0][r] = kv.x; SB[c + 1][r] = kv.y;
            SB[c + 2][r] = kv.z; SB[c + 3][r] = kv.w;
        }
        __syncthreads();

        float acc[4][4] = {};
#pragma unroll 8
        for (int d = 0; d < 64; ++d) {
            float4 a4 = *(const float4*)&SA[d][ty << 2];
            float4 b4 = *(const float4*)&SB[d][tx << 2];
            const float a[4] = {a4.x, a4.y, a4.z, a4.w};
            const float bb[4] = {b4.x, b4.y, b4.z, b4.w};
#pragma unroll
            for (int i = 0; i < 4; ++i)
#pragma unroll
                for (int j = 0; j < 4; ++j) acc[i][j] += a[i] * bb[j];
        }

        const int cc = c0 + (tx << 2);
        float mk[4];
#pragma unroll
        for (int j = 0; j < 4; ++j)
            mk[j] = (1.0f - amask[(size_t)b * Sn + cc + j]) * -10000.0f;

#pragma unroll
        for (int i = 0; i < 4; ++i) {
            const float s0 = acc[i][0] * gt[i] + mk[0];
            const float s1 = acc[i][1] * gt[i] + mk[1];
            const float s2 = acc[i][2] * gt[i] + mk[2];
            const float s3 = acc[i][3] * gt[i] + mk[3];
            const int qr = q0 + (ty << 2) + i;
            float4 o = {s0, s1, s2, s3};
            *(float4*)(P + (size_t)qr * Sn + cc) = o;

            float tmax = fmaxf(fmaxf(s0, s1), fmaxf(s2, s3));
#pragma unroll
            for (int w = 1; w < 16; w <<= 1)
                tmax = fmaxf(tmax, __shfl_xor(tmax, w, 16));
            const float nm = fmaxf(mrow[i], tmax);
            float ps = __expf(s0 - nm) + __expf(s1 - nm)
                     + __expf(s2 - nm) + __expf(s3 - nm);
#pragma unroll
            for (int w = 1; w < 16; w <<= 1)
                ps += __shfl_xor(ps, w, 16);
            lrow[i] = lrow[i] * __expf(mrow[i] - nm) + ps;
            mrow[i] = nm;
        }
    }

    float inv[4];
#pragma unroll
    for (int i = 0; i < 4; ++i) inv[i] = 1.0f / lrow[i];

    // ---- Pass 2: normalize + PV (reverse order: last-written tiles hottest) ----
    float cacc[4][4] = {};
    for (int kt = 31; kt >= 0; --kt) {
        const int c0 = kt << 6;
        __syncthreads();               // prev PV done before SB/SA overwrite
        // stage Vs[k][d]
#pragma unroll
        for (int t2 = 0; t2 < 4; ++t2) {
            const int f = tid + (t2 << 8);
            const int r = f >> 4;
            const int c = (f & 15) << 2;
            *(float4*)&SB[r][c] = *(const float4*)(V + (size_t)(c0 + r) * Hn + c);
        }
        // read raw tile back, normalize, write final probs, stash Ps[q][k]
        const int cc = c0 + (tx << 2);
#pragma unroll
        for (int i = 0; i < 4; ++i) {
            const int qr = q0 + (ty << 2) + i;
            float4 s = *(const float4*)(P + (size_t)qr * Sn + cc);
            float4 p;
            p.x = __expf(s.x - mrow[i]) * inv[i];
            p.y = __expf(s.y - mrow[i]) * inv[i];
            p.z = __expf(s.z - mrow[i]) * inv[i];
            p.w = __expf(s.w - mrow[i]) * inv[i];
            *(float4*)(P + (size_t)qr * Sn + cc) = p;
            *(float4*)&SA[(ty << 2) + i][tx << 2] = p;
        }
        __syncthreads();
        // PV: cacc[q][d] += Ps[q][kk] * Vs[kk][d]
#pragma unroll 4
        for (int kk = 0; kk < 64; kk += 4) {
            float4 a_[4], b_[4];
#pragma unroll
            for (int i = 0; i < 4; ++i)
                a_[i] = *(const float4*)&SA[(ty << 2) + i][kk];
#pragma unroll
            for (int t2 = 0; t2 < 4; ++t2)
                b_[t2] = *(const float4*)&SB[kk + t2][tx << 2];
#pragma unroll
            for (int i = 0; i < 4; ++i) {
                const float a0 = a_[i].x, a1 = a_[i].y, a2 = a_[i].z, a3 = a_[i].w;
#pragma unroll
                for (int j = 0; j < 4; ++j) {
                    const float* bj0 = &b_[0].x;
                    cacc[i][j] += a0 * (&b_[0].x)[j];
                    cacc[i][j] += a1 * (&b_[1].x)[j];
                    cacc[i][j] += a2 * (&b_[2].x)[j];
                    cacc[i][j] += a3 * (&b_[3].x)[j];
                    (void)bj0;
                }
            }
        }
    }

    // write ctx strip
#pragma unroll
    for (int i = 0; i < 4; ++i) {
        const int qr = q0 + (ty << 2) + i;
        float4 o;
        o.x = cacc[i][0]; o.y = cacc[i][1]; o.z = cacc[i][2]; o.w = cacc[i][3];
        *(float4*)(ctx + ((size_t)b * Sn + qr) * Hn + h * DHn + (tx << 2)) = o;
    }
}

// ---------------------------------------------------------------------------
// out = LayerNorm(ctxo + hidden) * lw + lb   (row length 768 = 3*256)
// ---------------------------------------------------------------------------
__global__ __launch_bounds__(256) void final_ln(const float* __restrict__ xo,
                                                const float* __restrict__ hs,
                                                const float* __restrict__ lw,
                                                const float* __restrict__ lb,
                                                float* __restrict__ out) {
    const int row = blockIdx.x;
    const int t = threadIdx.x;
    const float* a = xo + (size_t)row * Hn;
    const float* r = hs + (size_t)row * Hn;
    const float x0 = a[t] + r[t];
    const float x1 = a[t + 256] + r[t + 256];
    const float x2 = a[t + 512] + r[t + 512];
    __shared__ float red[256];
    red[t] = x0 + x1 + x2; __syncthreads();
    for (int s2 = 128; s2 > 0; s2 >>= 1) {
        if (t < s2) red[t] += red[t + s2];
        __syncthreads();
    }
    const float mu = red[0] * (1.0f / Hn);
    __syncthreads();
    const float d0 = x0 - mu, d1 = x1 - mu, d2 = x2 - mu;
    red[t] = d0 * d0 + d1 * d1 + d2 * d2; __syncthreads();
    for (int s2 = 128; s2 > 0; s2 >>= 1) {
        if (t < s2) red[t] += red[t + s2];
        __syncthreads();
    }
    const float rs = rsqrtf(red[0] * (1.0f / Hn) + EPSf);
    out[(size_t)row * Hn + t]       = d0 * rs * lw[t]       + lb[t];
    out[(size_t)row * Hn + t + 256] = d1 * rs * lw[t + 256] + lb[t + 256];
    out[(size_t)row * Hn + t + 512] = d2 * rs * lw[t + 512] + lb[t + 512];
}

// ---------------------------------------------------------------------------
extern "C" void kernel_launch(void* const* d_in, const int* in_sizes, int n_in,
                              void* d_out, int out_size, void* d_ws, size_t ws_size,
                              hipStream_t stream) {
    const float* hidden = (const float*)d_in[0];
    const float* amask  = (const float*)d_in[1];
    const float* Wq = (const float*)d_in[2];  const float* bq = (const float*)d_in[3];
    const float* Wk = (const float*)d_in[4];  const float* bk = (const float*)d_in[5];
    const float* Wv = (const float*)d_in[6];  const float* bv = (const float*)d_in[7];
    const float* Wg1 = (const float*)d_in[8]; const float* bg1 = (const float*)d_in[9];
    const float* glw = (const float*)d_in[10]; const float* glb = (const float*)d_in[11];
    const float* Wg2 = (const float*)d_in[12]; const float* bg2 = (const float*)d_in[13];
    const float* Wo = (const float*)d_in[14]; const float* bo = (const float*)d_in[15];
    const float* lw = (const float*)d_in[16]; const float* lb = (const float*)d_in[17];

    float* out   = (float*)d_out;                      // [8192,768]
    float* probs = out + (size_t)MR * Hn;              // [48,2048,2048]

    float* q     = (float*)d_ws;                       // [8192,768]
    float* k     = q + (size_t)MR * Hn;                // [8192,768]
    float* v     = k + (size_t)MR * Hn;                // [8192,768]
    float* g     = v + (size_t)MR * Hn;                // [8192,128]
    float* gates = g + (size_t)MR * WHn;               // [8192,12]
    // ctx lives in the `out` region (dead until final_ln); ctxo reuses q
    // (q is only read by attn_fused, which completes before the Wo GEMM).
    float* ctx   = out;
    float* ctxo  = q;

    dim3 blk(256);
    proj_gemm<<<dim3(Hn / 64, MR / 64), blk, 0, stream>>>(hidden, Wq, bq, q, MR, Hn, Hn);
    proj_gemm<<<dim3(Hn / 64, MR / 64), blk, 0, stream>>>(hidden, Wk, bk, k, MR, Hn, Hn);
    proj_gemm<<<dim3(Hn / 64, MR / 64), blk, 0, stream>>>(hidden, Wv, bv, v, MR, Hn, Hn);
    proj_gemm<<<dim3(WHn / 64, MR / 64), blk, 0, stream>>>(hidden, Wg1, bg1, g, MR, WHn, Hn);
    gate_kernel<<<dim3(MR), dim3(128), 0, stream>>>(g, glw, glb, Wg2, bg2, gates);
    attn_fused<<<dim3(Sn / 64, Bn * NHn), blk, 0, stream>>>(q, k, v, gates, amask, probs, ctx);
    proj_gemm<<<dim3(Hn / 64, MR / 64), blk, 0, stream>>>(ctx, Wo, bo, ctxo, MR, Hn, Hn);
    final_ln<<<dim3(MR), blk, 0, stream>>>(ctxo, hidden, lw, lb, out);
}